// Round 7
// baseline (1096.790 us; speedup 1.0000x reference)
//
#include <hip/hip_runtime.h>

constexpr int NN  = 5000;     // nodes
constexpr int NE  = 160000;   // edges
constexpr int NB_ = 8;        // batches
constexpr float RMAX   = 6.0f;
constexpr float INV_AVG = 1.0f/32.0f;
constexpr float SQ3  = 1.7320508075688772f;
constexpr float ISQ3 = 0.5773502691896258f;
constexpr float ISQ5 = 0.4472135954999579f;
constexpr float SQ15 = 3.872983346207417f;
constexpr float SQ5  = 2.2360679774997896f;
constexpr float PIF  = 3.14159265358979323846f;

__device__ __forceinline__ float sigmoid_f(float x){
    return 1.0f / (1.0f + __expf(-x));
}
__device__ __forceinline__ float silu_f(float x){ return x * sigmoid_f(x); }

// ---------------- K1: edge geometry (bessel*cutoff emb, Y1, Y2) + dst histogram
__global__ void k_geom(const float* __restrict__ pos, const int* __restrict__ ei,
                       float* __restrict__ geom, int* __restrict__ counts){
    int e = blockIdx.x*256 + threadIdx.x;
    if (e >= NE) return;
    int s = ei[e], d = ei[NE + e];
    float vx = pos[3*s]-pos[3*d], vy = pos[3*s+1]-pos[3*d+1], vz = pos[3*s+2]-pos[3*d+2];
    float r2 = vx*vx + vy*vy + vz*vz + 1e-12f;
    float r  = sqrtf(r2);
    float ir = 1.0f/r;
    float ux = vx*ir, uy = vy*ir, uz = vz*ir;
    float t  = fminf(r*(1.0f/RMAX), 1.0f);
    float t2=t*t, t3=t2*t, t6=t3*t3, t7=t6*t, t8=t7*t;
    float fc = (1.0f - 28.0f*t6 + 48.0f*t7 - 21.0f*t8) * (r < RMAX ? 1.0f : 0.0f);
    float cb = sqrtf(2.0f/RMAX) * ir * fc;
    float w[16];
    #pragma unroll
    for (int k=0;k<8;k++){
        float arg = (float)(k+1) * (PIF/RMAX) * r;
        w[k] = cb * sinf(arg);
    }
    w[8]  = SQ3*ux; w[9] = SQ3*uy; w[10] = SQ3*uz;
    w[11] = SQ15*ux*uy; w[12] = SQ15*uy*uz; w[13] = 0.5f*SQ5*(3.0f*uz*uz-1.0f);
    w[14] = SQ15*ux*uz; w[15] = 0.5f*SQ15*(ux*ux-uy*uy);
    float4* o = (float4*)(geom + (size_t)e*16);
    o[0] = make_float4(w[0],w[1],w[2],w[3]);
    o[1] = make_float4(w[4],w[5],w[6],w[7]);
    o[2] = make_float4(w[8],w[9],w[10],w[11]);
    o[3] = make_float4(w[12],w[13],w[14],w[15]);
    atomicAdd(&counts[d], 1);
}

// ---------------- K2: single-block exclusive scan
__global__ void k_scan(int* __restrict__ cr, int* __restrict__ fpos){
    __shared__ int part[256];
    int t = threadIdx.x;
    const int CH = (NN + 255)/256;   // 20
    int base = t*CH;
    int s = 0;
    for (int i=0;i<CH;i++){ int idx = base+i; if (idx < NN) s += cr[idx]; }
    part[t] = s; __syncthreads();
    for (int off=1; off<256; off<<=1){
        int v = (t >= off) ? part[t-off] : 0;
        __syncthreads();
        part[t] += v;
        __syncthreads();
    }
    int run = (t==0) ? 0 : part[t-1];
    for (int i=0;i<CH;i++){
        int idx = base+i;
        if (idx < NN){
            int c = cr[idx];
            cr[idx]  = run;
            fpos[idx] = run;
            run += c;
        } else if (idx == NN){
            cr[idx] = run;
        }
    }
}

// ---------------- K3: fill CSR edge list
__global__ void k_fill(const int* __restrict__ ei, int* __restrict__ fpos,
                       int* __restrict__ elist, int* __restrict__ slot){
    int e = blockIdx.x*256 + threadIdx.x;
    if (e >= NE) return;
    int d = ei[NE+e];
    int p = atomicAdd(&fpos[d], 1);
    elist[p] = e;
    slot[e]  = p;
}

// ---------------- K4: s = x @ W_in
__global__ void k_sinit(const float* __restrict__ x, const float* __restrict__ Win,
                        float* __restrict__ sA){
    int tid = blockIdx.x*256 + threadIdx.x;
    int n = tid >> 5, o = tid & 31;
    if (n >= NN) return;
    float a = 0.f;
    #pragma unroll
    for (int k=0;k<64;k++) a = fmaf(x[n*64+k], Win[k*32+o], a);
    sA[n*32+o] = a;
}

// ---------------- K5: LDS-tiled edge radial MLP (unchanged from R6)
__launch_bounds__(256, 4)
__global__ void k_mlp(const float* __restrict__ geom, const int* __restrict__ slot,
                      const float* __restrict__ Wr1, const float* __restrict__ br1,
                      const float* __restrict__ Wr2, const float* __restrict__ br2,
                      const float* __restrict__ Wr3, const float* __restrict__ br3,
                      float* __restrict__ wbuf, int layer){
    __shared__ __align__(16) float w1s[8*64];
    __shared__ __align__(16) float w2s[64*64];   // phase C: aliased as W3 chunk
    __shared__ __align__(16) float b1s[64], b2s[64];
    __shared__ __align__(16) float b3s[144];
    __shared__ __align__(16) float embs[64][8];
    __shared__ __align__(16) float hs[64][68];
    __shared__ int   slots[64];

    const int t  = threadIdx.x;
    const int e0 = blockIdx.x * 64;
    const float* W1 = Wr1 + layer*(8*64);
    const float* b1 = br1 + layer*64;
    const float* W2 = Wr2 + layer*(64*64);
    const float* b2 = br2 + layer*64;
    const float* W3 = Wr3 + layer*(64*144);
    const float* b3 = br3 + layer*144;

    {
        const float4* W2v = (const float4*)W2;
        float4* w2v = (float4*)w2s;
        #pragma unroll
        for (int i=0;i<4;i++) w2v[t + 256*i] = W2v[t + 256*i];
        if (t < 128) ((float4*)w1s)[t] = ((const float4*)W1)[t];
        if (t < 64){ b1s[t] = b1[t]; b2s[t] = b2[t]; slots[t] = slot[e0 + t]; }
        if (t < 144) b3s[t] = b3[t];
        if (t < 128){
            ((float4*)embs)[t] = *((const float4*)geom + (size_t)(e0 + (t>>1))*4 + (t&1));
        }
    }
    __syncthreads();

    const int eg = t >> 3;
    const int jg = t & 7;
    const int ea = eg*2, eb = ea+1;

    float a0[2][8];
    #pragma unroll
    for (int i=0;i<2;i++)
        #pragma unroll
        for (int u=0;u<8;u++) a0[i][u] = b1s[8*jg+u];
    #pragma unroll
    for (int k=0;k<8;k++){
        float e_a = embs[ea][k], e_b = embs[eb][k];
        #pragma unroll
        for (int u=0;u<8;u++){
            float wv = w1s[k*64 + 8*jg + u];
            a0[0][u] = fmaf(e_a, wv, a0[0][u]);
            a0[1][u] = fmaf(e_b, wv, a0[1][u]);
        }
    }
    #pragma unroll
    for (int i=0;i<2;i++){
        int e = ea + i;
        float4 p0 = make_float4(silu_f(a0[i][0]), silu_f(a0[i][1]), silu_f(a0[i][2]), silu_f(a0[i][3]));
        float4 p1 = make_float4(silu_f(a0[i][4]), silu_f(a0[i][5]), silu_f(a0[i][6]), silu_f(a0[i][7]));
        *(float4*)&hs[e][8*jg]     = p0;
        *(float4*)&hs[e][8*jg + 4] = p1;
    }
    __syncthreads();

    float a1[2][8];
    #pragma unroll
    for (int i=0;i<2;i++)
        #pragma unroll
        for (int u=0;u<8;u++) a1[i][u] = b2s[8*jg+u];
    #pragma unroll
    for (int k=0;k<64;k++){
        float h_a = hs[ea][k], h_b = hs[eb][k];
        float4 wA = *(const float4*)&w2s[k*64 + 8*jg];
        float4 wB = *(const float4*)&w2s[k*64 + 8*jg + 4];
        a1[0][0]=fmaf(h_a,wA.x,a1[0][0]); a1[0][1]=fmaf(h_a,wA.y,a1[0][1]);
        a1[0][2]=fmaf(h_a,wA.z,a1[0][2]); a1[0][3]=fmaf(h_a,wA.w,a1[0][3]);
        a1[0][4]=fmaf(h_a,wB.x,a1[0][4]); a1[0][5]=fmaf(h_a,wB.y,a1[0][5]);
        a1[0][6]=fmaf(h_a,wB.z,a1[0][6]); a1[0][7]=fmaf(h_a,wB.w,a1[0][7]);
        a1[1][0]=fmaf(h_b,wA.x,a1[1][0]); a1[1][1]=fmaf(h_b,wA.y,a1[1][1]);
        a1[1][2]=fmaf(h_b,wA.z,a1[1][2]); a1[1][3]=fmaf(h_b,wA.w,a1[1][3]);
        a1[1][4]=fmaf(h_b,wB.x,a1[1][4]); a1[1][5]=fmaf(h_b,wB.y,a1[1][5]);
        a1[1][6]=fmaf(h_b,wB.z,a1[1][6]); a1[1][7]=fmaf(h_b,wB.w,a1[1][7]);
    }
    __syncthreads();
    #pragma unroll
    for (int i=0;i<2;i++){
        int e = ea + i;
        float4 p0 = make_float4(silu_f(a1[i][0]), silu_f(a1[i][1]), silu_f(a1[i][2]), silu_f(a1[i][3]));
        float4 p1 = make_float4(silu_f(a1[i][4]), silu_f(a1[i][5]), silu_f(a1[i][6]), silu_f(a1[i][7]));
        *(float4*)&hs[e][8*jg]     = p0;
        *(float4*)&hs[e][8*jg + 4] = p1;
    }
    __syncthreads();

    float c2[2][18];
    #pragma unroll
    for (int i=0;i<2;i++)
        #pragma unroll
        for (int u=0;u<18;u++) c2[i][u] = b3s[18*jg+u];

    float* w3c = w2s;
    for (int ch=0; ch<4; ++ch){
        const float4* src = (const float4*)(W3 + 16*ch*144);
        float4* dst = (float4*)w3c;
        dst[t]       = src[t];
        dst[t+256]   = src[t+256];
        if (t < 64) dst[t+512] = src[t+512];
        __syncthreads();
        #pragma unroll
        for (int kk=0;kk<16;kk++){
            int k = 16*ch + kk;
            float h_a = hs[ea][k], h_b = hs[eb][k];
            #pragma unroll
            for (int u2=0;u2<9;u2++){
                float2 wv = *(const float2*)&w3c[kk*144 + 18*jg + 2*u2];
                c2[0][2*u2]   = fmaf(h_a, wv.x, c2[0][2*u2]);
                c2[0][2*u2+1] = fmaf(h_a, wv.y, c2[0][2*u2+1]);
                c2[1][2*u2]   = fmaf(h_b, wv.x, c2[1][2*u2]);
                c2[1][2*u2+1] = fmaf(h_b, wv.y, c2[1][2*u2+1]);
            }
        }
        __syncthreads();
    }
    #pragma unroll
    for (int i=0;i<2;i++){
        float* wo = wbuf + (size_t)slots[ea+i]*144 + 18*jg;
        #pragma unroll
        for (int u2=0;u2<9;u2++)
            *(float2*)(wo + 2*u2) = make_float2(c2[i][2*u2], c2[i][2*u2+1]);
    }
}

// ---------------- K6: per-dst gather + fused node update
// 512 threads = 8 waves/node; pair-unrolled edge loop for memory-level parallelism
__launch_bounds__(512, 4)
__global__ void k_gather(const int* __restrict__ rowp, const int* __restrict__ elist,
                         const int* __restrict__ ei, const float* __restrict__ geom,
                         const float* __restrict__ wbuf,
                         const float* __restrict__ s_in, const float* __restrict__ v_in,
                         const float* __restrict__ q_in,
                         float* __restrict__ s_out, float* __restrict__ v_out,
                         float* __restrict__ q_out,
                         const float* __restrict__ Wm0, const float* __restrict__ Wm1,
                         const float* __restrict__ Wm2,
                         const float* __restrict__ Ws0, const float* __restrict__ Ws1,
                         const float* __restrict__ Ws2,
                         const float* __restrict__ Wg, const float* __restrict__ bg,
                         int layer){
    __shared__ float pacc[8][400];
    __shared__ float lacc[400];
    __shared__ float lns[32];
    __shared__ float lgate[24];
    const int n = blockIdx.x;
    const int t = threadIdx.x;
    const int w = t >> 6;        // 0..7
    const int lane = t & 63;

    int s0_w, s0_o, s0_ob;
    if (lane < 32){ s0_w = lane;            s0_o = lane;          s0_ob = lane; }
    else if (lane < 48){ s0_w = 112+(lane-32); s0_o = 3*(lane-32); s0_ob = lane; }
    else if (lane < 56){ s0_w = 136+(lane-48); s0_o = 5*(lane-48); s0_ob = lane; }
    else { int R = lane-56; s0_w = 32+R; s0_o = R; s0_ob = 56+3*R; }
    int s1_w, s1_o, s1_ob;
    if (lane < 24){ int R = lane+8; s1_w = 32+R; s1_o = R;     s1_ob = 56+3*R; }
    else if (lane < 40){ int j = lane-24; s1_w = 96+j; s1_o = 3*j; s1_ob = 152+3*j; }
    else { int R = lane-40; s1_w = 64+R; s1_o = R; s1_ob = 200+5*R; }
    int s2_w, s2_o, s2_ob;
    if (lane < 8){ int R = lane+24; s2_w = 64+R; s2_o = R;   s2_ob = 200+5*R; }
    else { int j = lane-8; s2_w = 128+j; s2_o = 5*j; s2_ob = 360+5*j; }

    float a0[3] = {0.f,0.f,0.f};
    float a1[5] = {0.f,0.f,0.f,0.f,0.f};
    float a2[5] = {0.f,0.f,0.f,0.f,0.f};

    auto body = [&](int idx){
        int e   = elist[idx];
        int src = ei[e];
        const float* gp = geom + (size_t)e*16;
        float4 y14 = *(const float4*)(gp + 8);
        float4 y58 = *(const float4*)(gp + 12);
        const float* wp = wbuf + (size_t)idx*144;
        const float* sp = s_in + (size_t)src*32;
        const float* vp = v_in + (size_t)src*48;
        const float* qp = q_in + (size_t)src*40;
        {
            float wv = wp[s0_w];
            if (lane < 32){
                a0[0] = fmaf(wv, sp[s0_o], a0[0]);
            } else if (lane < 48){
                float dv = vp[s0_o]*y14.x + vp[s0_o+1]*y14.y + vp[s0_o+2]*y14.z;
                a0[0] = fmaf(wv*ISQ3, dv, a0[0]);
            } else if (lane < 56){
                float dq = qp[s0_o]*y14.w + qp[s0_o+1]*y58.x + qp[s0_o+2]*y58.y
                         + qp[s0_o+3]*y58.z + qp[s0_o+4]*y58.w;
                a0[0] = fmaf(wv*ISQ5, dq, a0[0]);
            } else {
                float tmp = wv * sp[s0_o];
                a0[0] = fmaf(tmp, y14.x, a0[0]);
                a0[1] = fmaf(tmp, y14.y, a0[1]);
                a0[2] = fmaf(tmp, y14.z, a0[2]);
            }
        }
        {
            float wv = wp[s1_w];
            if (lane < 24){
                float tmp = wv * sp[s1_o];
                a1[0] = fmaf(tmp, y14.x, a1[0]);
                a1[1] = fmaf(tmp, y14.y, a1[1]);
                a1[2] = fmaf(tmp, y14.z, a1[2]);
            } else if (lane < 40){
                a1[0] = fmaf(wv, vp[s1_o],   a1[0]);
                a1[1] = fmaf(wv, vp[s1_o+1], a1[1]);
                a1[2] = fmaf(wv, vp[s1_o+2], a1[2]);
            } else {
                float tmp = wv * sp[s1_o];
                a1[0] = fmaf(tmp, y14.w, a1[0]);
                a1[1] = fmaf(tmp, y58.x, a1[1]);
                a1[2] = fmaf(tmp, y58.y, a1[2]);
                a1[3] = fmaf(tmp, y58.z, a1[3]);
                a1[4] = fmaf(tmp, y58.w, a1[4]);
            }
        }
        if (lane < 16){
            float wv = wp[s2_w];
            if (lane < 8){
                float tmp = wv * sp[s2_o];
                a2[0] = fmaf(tmp, y14.w, a2[0]);
                a2[1] = fmaf(tmp, y58.x, a2[1]);
                a2[2] = fmaf(tmp, y58.y, a2[2]);
                a2[3] = fmaf(tmp, y58.z, a2[3]);
                a2[4] = fmaf(tmp, y58.w, a2[4]);
            } else {
                a2[0] = fmaf(wv, qp[s2_o],   a2[0]);
                a2[1] = fmaf(wv, qp[s2_o+1], a2[1]);
                a2[2] = fmaf(wv, qp[s2_o+2], a2[2]);
                a2[3] = fmaf(wv, qp[s2_o+3], a2[3]);
                a2[4] = fmaf(wv, qp[s2_o+4], a2[4]);
            }
        }
    };

    const int beg = rowp[n], end = rowp[n+1];
    int idx = beg + w;
    for (; idx + 8 < end; idx += 16){   // both bodies unguarded -> compiler interleaves loads
        body(idx);
        body(idx + 8);
    }
    if (idx < end) body(idx);

    pacc[w][s0_ob] = a0[0];
    if (lane >= 56){ pacc[w][s0_ob+1] = a0[1]; pacc[w][s0_ob+2] = a0[2]; }
    pacc[w][s1_ob] = a1[0]; pacc[w][s1_ob+1] = a1[1]; pacc[w][s1_ob+2] = a1[2];
    if (lane >= 40){ pacc[w][s1_ob+3] = a1[3]; pacc[w][s1_ob+4] = a1[4]; }
    if (lane < 16){
        #pragma unroll
        for (int u=0;u<5;u++) pacc[w][s2_ob+u] = a2[u];
    }
    __syncthreads();
    for (int c=t; c<400; c+=512){
        float s8 = 0.f;
        #pragma unroll
        for (int g=0; g<8; g++) s8 += pacc[g][c];
        lacc[c] = s8 * INV_AVG;
    }
    __syncthreads();

    const float* Wm0p = Wm0 + layer*(56*32);
    const float* Ws0p = Ws0 + layer*(32*32);
    const float* Wm1p = Wm1 + layer*(48*16);
    const float* Ws1p = Ws1 + layer*(16*16);
    const float* Wm2p = Wm2 + layer*(40*8);
    const float* Ws2p = Ws2 + layer*(8*8);
    const float* Wgp  = Wg  + layer*(32*24);
    const float* bgp  = bg  + layer*24;

    float nvv = 0.f, nqv = 0.f;
    if (t < 32){
        float a = 0.f;
        #pragma unroll
        for (int c=0;c<56;c++) a = fmaf(lacc[c], Wm0p[c*32+t], a);
        #pragma unroll
        for (int c=0;c<32;c++) a = fmaf(s_in[n*32+c], Ws0p[c*32+t], a);
        lns[t] = a;
    } else if (t >= 64 && t < 112){
        int o = t-64, o3 = o/3, m3 = o-3*o3;
        #pragma unroll
        for (int c=0;c<48;c++) nvv = fmaf(lacc[56+c*3+m3], Wm1p[c*16+o3], nvv);
        #pragma unroll
        for (int c=0;c<16;c++) nvv = fmaf(v_in[n*48+c*3+m3], Ws1p[c*16+o3], nvv);
    } else if (t >= 128 && t < 168){
        int o = t-128, o5 = o/5, m5 = o-5*o5;
        #pragma unroll
        for (int c=0;c<40;c++) nqv = fmaf(lacc[200+c*5+m5], Wm2p[c*8+o5], nqv);
        #pragma unroll
        for (int c=0;c<8;c++)  nqv = fmaf(q_in[n*40+c*5+m5], Ws2p[c*8+o5], nqv);
    }
    __syncthreads();
    if (t < 24){
        float a = bgp[t];
        #pragma unroll
        for (int c=0;c<32;c++) a = fmaf(lns[c], Wgp[c*24+t], a);
        lgate[t] = sigmoid_f(a);
    }
    __syncthreads();
    if (t < 32){
        s_out[n*32+t] = s_in[n*32+t] + silu_f(lns[t]);
    } else if (t >= 64 && t < 112){
        int o = t-64;
        v_out[n*48+o] = v_in[n*48+o] + nvv * lgate[o/3];
    } else if (t >= 128 && t < 168){
        int o = t-128;
        q_out[n*40+o] = q_in[n*40+o] + nqv * lgate[16+o/5];
    }
}

// ---------------- K7: pooling MLP -> per-node logit
__launch_bounds__(128)
__global__ void k_pool(const float* __restrict__ s_in,
                       const float* __restrict__ Wp1, const float* __restrict__ bp1,
                       const float* __restrict__ Wp2, const float* __restrict__ bp2,
                       const float* __restrict__ Wp3, const float* __restrict__ bp3,
                       float* __restrict__ logits){
    __shared__ float ls[32];
    __shared__ float lh[128];
    __shared__ float wred[2];
    int n = blockIdx.x, t = threadIdx.x;
    if (t < 32) ls[t] = s_in[n*32+t];
    __syncthreads();
    float a = bp1[t];
    #pragma unroll
    for (int c=0;c<32;c++) a = fmaf(ls[c], Wp1[c*128+t], a);
    lh[t] = silu_f(a);
    __syncthreads();
    float b = bp2[t];
    #pragma unroll
    for (int k=0;k<128;k++) b = fmaf(lh[k], Wp2[k*128+t], b);
    float p = silu_f(b) * Wp3[t];
    #pragma unroll
    for (int off=32; off>0; off>>=1) p += __shfl_down(p, off, 64);
    if ((t & 63) == 0) wred[t>>6] = p;
    __syncthreads();
    if (t == 0) logits[n] = wred[0] + wred[1] + bp3[0];
}

// ---------------- K8r: batch ranges (batch is sorted)
__global__ void k_ranges(const int* __restrict__ batch, int* __restrict__ rs, int* __restrict__ re){
    int n = blockIdx.x*256 + threadIdx.x;
    if (n >= NN) return;
    int b = batch[n];
    if (n == 0 || batch[n-1] != b) rs[b] = n;
    if (n == NN-1 || batch[n+1] != b) re[b] = n+1;
}

// ---------------- K8: fused softmax-attention pool (max, z, denom, weighted sum)
__launch_bounds__(1024)
__global__ void k_spool(const float* __restrict__ logits, const float* __restrict__ s_in,
                        const int* __restrict__ rs, const int* __restrict__ re,
                        float* __restrict__ gpool){
    __shared__ float red[1024];
    __shared__ float racc[32*33];
    __shared__ float dred[32];
    __shared__ float smx;
    int b = blockIdx.x, t = threadIdx.x;
    int lo = rs[b], hi = re[b];
    float m = -3.0e38f;
    for (int n = lo + t; n < hi; n += 1024) m = fmaxf(m, logits[n]);
    red[t] = m; __syncthreads();
    for (int s2=512; s2>0; s2>>=1){ if (t<s2) red[t] = fmaxf(red[t], red[t+s2]); __syncthreads(); }
    if (t==0) smx = red[0];
    __syncthreads();
    float mx = smx;
    int g = t >> 5, c = t & 31;   // 32 groups x 32 channels
    float acc = 0.f, zs = 0.f;
    for (int n = lo + g; n < hi; n += 32){
        float z = __expf(logits[n] - mx);
        acc = fmaf(z, s_in[n*32+c], acc);
        zs += z;
    }
    racc[g*33+c] = acc;
    if (c == 0) dred[g] = zs;
    __syncthreads();
    if (t < 32){
        float a = 0.f, d = 0.f;
        #pragma unroll
        for (int g2=0; g2<32; g2++){ a += racc[g2*33+t]; d += dred[g2]; }
        gpool[b*32+t] = a / d;
    }
}

// ---------------- K9a: h = silu(LN(gpool@Wo1+bo1))
__launch_bounds__(1024)
__global__ void k_out1(const float* __restrict__ gpool, const float* __restrict__ Wo1,
                       const float* __restrict__ bo1, const float* __restrict__ g1,
                       const float* __restrict__ be1, float* __restrict__ hbuf){
    __shared__ float lg[32];
    __shared__ float red[1024];
    __shared__ float stats[2];
    int b = blockIdx.x, t = threadIdx.x;
    if (t < 32) lg[t] = gpool[b*32+t];
    __syncthreads();
    float a = bo1[t];
    #pragma unroll
    for (int c=0;c<32;c++) a = fmaf(lg[c], Wo1[c*1024+t], a);
    red[t] = a; __syncthreads();
    for (int s2=512; s2>0; s2>>=1){ if (t<s2) red[t]+=red[t+s2]; __syncthreads(); }
    if (t==0) stats[0] = red[0]*(1.0f/1024.0f);
    __syncthreads();
    float mean = stats[0];
    float d = a - mean;
    red[t] = d*d; __syncthreads();
    for (int s2=512; s2>0; s2>>=1){ if (t<s2) red[t]+=red[t+s2]; __syncthreads(); }
    if (t==0) stats[1] = red[0]*(1.0f/1024.0f);
    __syncthreads();
    float rstd = rsqrtf(stats[1] + 1e-5f);
    hbuf[b*1024+t] = silu_f(d*rstd*g1[t] + be1[t]);
}

// ---------------- K9b: out = LN(h@Wo2+bo2), split-k=2
__launch_bounds__(1024)
__global__ void k_out2(const float* __restrict__ hbuf, const float* __restrict__ Wo2,
                       const float* __restrict__ bo2, const float* __restrict__ g2,
                       const float* __restrict__ be2, float* __restrict__ out){
    __shared__ float lh[1024];
    __shared__ float part[1024];
    __shared__ float red[1024];
    __shared__ float stats[2];
    int b = blockIdx.x, t = threadIdx.x;
    lh[t] = hbuf[b*1024 + t];
    __syncthreads();
    int j = t & 511, half = t >> 9;
    float a = (half == 0) ? bo2[j] : 0.0f;
    int k0 = half*512;
    #pragma unroll 8
    for (int k=0;k<512;k++) a = fmaf(lh[k0+k], Wo2[(size_t)(k0+k)*512 + j], a);
    part[t] = a; __syncthreads();
    float y = 0.f;
    if (t < 512) y = part[t] + part[t+512];
    red[t] = (t < 512) ? y : 0.f; __syncthreads();
    for (int s2=512; s2>0; s2>>=1){ if (t<s2) red[t]+=red[t+s2]; __syncthreads(); }
    if (t==0) stats[0] = red[0]*(1.0f/512.0f);
    __syncthreads();
    float mean = stats[0];
    float d = y - mean;
    red[t] = (t < 512) ? d*d : 0.f; __syncthreads();
    for (int s2=512; s2>0; s2>>=1){ if (t<s2) red[t]+=red[t+s2]; __syncthreads(); }
    if (t==0) stats[1] = red[0]*(1.0f/512.0f);
    __syncthreads();
    float rstd = rsqrtf(stats[1] + 1e-5f);
    if (t < 512) out[b*512+t] = d*rstd*g2[t] + be2[t];
}

extern "C" void kernel_launch(void* const* d_in, const int* in_sizes, int n_in,
                              void* d_out, int out_size, void* d_ws, size_t ws_size,
                              hipStream_t stream){
    const float* x   = (const float*)d_in[0];
    const float* pos = (const float*)d_in[1];
    const float* Win = (const float*)d_in[2];
    const float* Wr1 = (const float*)d_in[3];
    const float* br1 = (const float*)d_in[4];
    const float* Wr2 = (const float*)d_in[5];
    const float* br2 = (const float*)d_in[6];
    const float* Wr3 = (const float*)d_in[7];
    const float* br3 = (const float*)d_in[8];
    const float* Wm0 = (const float*)d_in[9];
    const float* Wm1 = (const float*)d_in[10];
    const float* Wm2 = (const float*)d_in[11];
    const float* Ws0 = (const float*)d_in[12];
    const float* Ws1 = (const float*)d_in[13];
    const float* Ws2 = (const float*)d_in[14];
    const float* Wg  = (const float*)d_in[15];
    const float* bg  = (const float*)d_in[16];
    const float* Wp1 = (const float*)d_in[17];
    const float* bp1 = (const float*)d_in[18];
    const float* Wp2 = (const float*)d_in[19];
    const float* bp2 = (const float*)d_in[20];
    const float* Wp3 = (const float*)d_in[21];
    const float* bp3 = (const float*)d_in[22];
    const float* Wo1 = (const float*)d_in[23];
    const float* bo1 = (const float*)d_in[24];
    const float* g1  = (const float*)d_in[25];
    const float* be1 = (const float*)d_in[26];
    const float* Wo2 = (const float*)d_in[27];
    const float* bo2 = (const float*)d_in[28];
    const float* g2  = (const float*)d_in[29];
    const float* be2 = (const float*)d_in[30];
    const int* ei    = (const int*)d_in[31];
    const int* batch = (const int*)d_in[32];
    float* out = (float*)d_out;

    char* wsb = (char*)d_ws;
    size_t off = 0;
    auto take = [&](size_t bytes)->char*{
        char* p = wsb + off;
        off = (off + bytes + 255) & ~(size_t)255;
        return p;
    };
    float* geom  = (float*)take((size_t)NE*16*4);
    float* wbuf  = (float*)take((size_t)NE*144*4);
    int*   rowp  = (int*)take((size_t)(NN+1)*4);
    int*   fpos  = (int*)take((size_t)NN*4);
    int*   elist = (int*)take((size_t)NE*4);
    int*   slot  = (int*)take((size_t)NE*4);
    // vA (960000 B, multiple of 256) then qA immediately after -> one memset covers both
    float* vA = (float*)take((size_t)NN*48*4);
    float* qA = (float*)take((size_t)NN*40*4);
    float* sA = (float*)take((size_t)NN*32*4);
    float* sB = (float*)take((size_t)NN*32*4);
    float* vB = (float*)take((size_t)NN*48*4);
    float* qB = (float*)take((size_t)NN*40*4);
    float* logits = (float*)take((size_t)NN*4);
    int*   rs     = (int*)take(64);           // rs[0..7], re[0..7] in one 64B block
    int*   re     = rs + 8;
    float* gpool  = (float*)take((size_t)NB_*32*4);
    float* hbuf   = (float*)take((size_t)NB_*1024*4);
    (void)ws_size; (void)in_sizes; (void)n_in; (void)out_size;

    hipMemsetAsync(rowp, 0, (size_t)(NN+1)*4, stream);
    hipMemsetAsync(vA,   0, (size_t)NN*48*4 + (size_t)NN*40*4, stream);  // vA + qA
    hipMemsetAsync(rs,   0, 64, stream);                                  // rs + re

    k_geom<<<(NE+255)/256, 256, 0, stream>>>(pos, ei, geom, rowp);
    k_scan<<<1, 256, 0, stream>>>(rowp, fpos);
    k_fill<<<(NE+255)/256, 256, 0, stream>>>(ei, fpos, elist, slot);
    k_sinit<<<(NN*32+255)/256, 256, 0, stream>>>(x, Win, sA);
    k_ranges<<<(NN+255)/256, 256, 0, stream>>>(batch, rs, re);

    float* si=sA; float* so=sB; float* vi=vA; float* vo=vB; float* qi=qA; float* qo=qB;
    for (int layer=0; layer<4; ++layer){
        k_mlp<<<NE/64, 256, 0, stream>>>(geom, slot, Wr1, br1, Wr2, br2, Wr3, br3, wbuf, layer);
        k_gather<<<NN, 512, 0, stream>>>(rowp, elist, ei, geom, wbuf, si, vi, qi, so, vo, qo,
                                         Wm0, Wm1, Wm2, Ws0, Ws1, Ws2, Wg, bg, layer);
        float* ts=si; si=so; so=ts;
        float* tv=vi; vi=vo; vo=tv;
        float* tq=qi; qi=qo; qo=tq;
    }
    k_pool<<<NN, 128, 0, stream>>>(si, Wp1, bp1, Wp2, bp2, Wp3, bp3, logits);
    k_spool<<<NB_, 1024, 0, stream>>>(logits, si, rs, re, gpool);
    k_out1<<<NB_, 1024, 0, stream>>>(gpool, Wo1, bo1, g1, be1, hbuf);
    k_out2<<<NB_, 1024, 0, stream>>>(hbuf, Wo2, bo2, g2, be2, out);
}

// Round 9
// 1005.552 us; speedup vs baseline: 1.0907x; 1.0907x over previous
//
#include <hip/hip_runtime.h>

constexpr int NN  = 5000;     // nodes
constexpr int NE  = 160000;   // edges
constexpr int NB_ = 8;        // batches
constexpr int WROW = 160;     // wbuf row stride (144 w + 8 Y + pad), 640B aligned
constexpr float RMAX   = 6.0f;
constexpr float INV_AVG = 1.0f/32.0f;
constexpr float SQ3  = 1.7320508075688772f;
constexpr float ISQ3 = 0.5773502691896258f;
constexpr float ISQ5 = 0.4472135954999579f;
constexpr float SQ15 = 3.872983346207417f;
constexpr float SQ5  = 2.2360679774997896f;
constexpr float PIF  = 3.14159265358979323846f;

__device__ __forceinline__ float sigmoid_f(float x){
    return 1.0f / (1.0f + __expf(-x));
}
__device__ __forceinline__ float silu_f(float x){ return x * sigmoid_f(x); }

// ---------------- K1: edge geometry (bessel*cutoff emb, Y1, Y2) + dst histogram
__global__ void k_geom(const float* __restrict__ pos, const int* __restrict__ ei,
                       float* __restrict__ geom, int* __restrict__ counts){
    int e = blockIdx.x*256 + threadIdx.x;
    if (e >= NE) return;
    int s = ei[e], d = ei[NE + e];
    float vx = pos[3*s]-pos[3*d], vy = pos[3*s+1]-pos[3*d+1], vz = pos[3*s+2]-pos[3*d+2];
    float r2 = vx*vx + vy*vy + vz*vz + 1e-12f;
    float r  = sqrtf(r2);
    float ir = 1.0f/r;
    float ux = vx*ir, uy = vy*ir, uz = vz*ir;
    float t  = fminf(r*(1.0f/RMAX), 1.0f);
    float t2=t*t, t3=t2*t, t6=t3*t3, t7=t6*t, t8=t7*t;
    float fc = (1.0f - 28.0f*t6 + 48.0f*t7 - 21.0f*t8) * (r < RMAX ? 1.0f : 0.0f);
    float cb = sqrtf(2.0f/RMAX) * ir * fc;
    float w[16];
    #pragma unroll
    for (int k=0;k<8;k++){
        float arg = (float)(k+1) * (PIF/RMAX) * r;
        w[k] = cb * sinf(arg);
    }
    w[8]  = SQ3*ux; w[9] = SQ3*uy; w[10] = SQ3*uz;
    w[11] = SQ15*ux*uy; w[12] = SQ15*uy*uz; w[13] = 0.5f*SQ5*(3.0f*uz*uz-1.0f);
    w[14] = SQ15*ux*uz; w[15] = 0.5f*SQ15*(ux*ux-uy*uy);
    float4* o = (float4*)(geom + (size_t)e*16);
    o[0] = make_float4(w[0],w[1],w[2],w[3]);
    o[1] = make_float4(w[4],w[5],w[6],w[7]);
    o[2] = make_float4(w[8],w[9],w[10],w[11]);
    o[3] = make_float4(w[12],w[13],w[14],w[15]);
    atomicAdd(&counts[d], 1);
}

// ---------------- K2: single-block exclusive scan
__global__ void k_scan(int* __restrict__ cr, int* __restrict__ fpos){
    __shared__ int part[256];
    int t = threadIdx.x;
    const int CH = (NN + 255)/256;   // 20
    int base = t*CH;
    int s = 0;
    for (int i=0;i<CH;i++){ int idx = base+i; if (idx < NN) s += cr[idx]; }
    part[t] = s; __syncthreads();
    for (int off=1; off<256; off<<=1){
        int v = (t >= off) ? part[t-off] : 0;
        __syncthreads();
        part[t] += v;
        __syncthreads();
    }
    int run = (t==0) ? 0 : part[t-1];
    for (int i=0;i<CH;i++){
        int idx = base+i;
        if (idx < NN){
            int c = cr[idx];
            cr[idx]  = run;
            fpos[idx] = run;
            run += c;
        } else if (idx == NN){
            cr[idx] = run;
        }
    }
}

// ---------------- K3: fill CSR: slot per edge + src permuted to CSR order
__global__ void k_fill(const int* __restrict__ ei, int* __restrict__ fpos,
                       int* __restrict__ slot, int* __restrict__ srcp){
    int e = blockIdx.x*256 + threadIdx.x;
    if (e >= NE) return;
    int d = ei[NE+e];
    int p = atomicAdd(&fpos[d], 1);
    slot[e]  = p;
    srcp[p]  = ei[e];
}

// ---------------- K4: s = x @ W_in
__global__ void k_sinit(const float* __restrict__ x, const float* __restrict__ Win,
                        float* __restrict__ sA){
    int tid = blockIdx.x*256 + threadIdx.x;
    int n = tid >> 5, o = tid & 31;
    if (n >= NN) return;
    float a = 0.f;
    #pragma unroll
    for (int k=0;k<64;k++) a = fmaf(x[n*64+k], Win[k*32+o], a);
    sA[n*32+o] = a;
}

// ---------------- K5: LDS-tiled edge radial MLP; writes w + Y into CSR-ordered wbuf rows
__launch_bounds__(256, 4)
__global__ void k_mlp(const float* __restrict__ geom, const int* __restrict__ slot,
                      const float* __restrict__ Wr1, const float* __restrict__ br1,
                      const float* __restrict__ Wr2, const float* __restrict__ br2,
                      const float* __restrict__ Wr3, const float* __restrict__ br3,
                      float* __restrict__ wbuf, int layer){
    __shared__ __align__(16) float w1s[8*64];
    __shared__ __align__(16) float w2s[64*64];   // phase C: aliased as W3 chunk
    __shared__ __align__(16) float b1s[64], b2s[64];
    __shared__ __align__(16) float b3s[144];
    __shared__ __align__(16) float embs[64][8];
    __shared__ __align__(16) float hs[64][68];
    __shared__ int   slots[64];

    const int t  = threadIdx.x;
    const int e0 = blockIdx.x * 64;
    const float* W1 = Wr1 + layer*(8*64);
    const float* b1 = br1 + layer*64;
    const float* W2 = Wr2 + layer*(64*64);
    const float* b2 = br2 + layer*64;
    const float* W3 = Wr3 + layer*(64*144);
    const float* b3 = br3 + layer*144;

    {
        const float4* W2v = (const float4*)W2;
        float4* w2v = (float4*)w2s;
        #pragma unroll
        for (int i=0;i<4;i++) w2v[t + 256*i] = W2v[t + 256*i];
        if (t < 128) ((float4*)w1s)[t] = ((const float4*)W1)[t];
        if (t < 64){ b1s[t] = b1[t]; b2s[t] = b2[t]; slots[t] = slot[e0 + t]; }
        if (t < 144) b3s[t] = b3[t];
        if (t < 128){
            ((float4*)embs)[t] = *((const float4*)geom + (size_t)(e0 + (t>>1))*4 + (t&1));
        }
    }
    __syncthreads();

    const int eg = t >> 3;
    const int jg = t & 7;
    const int ea = eg*2, eb = ea+1;

    float a0[2][8];
    #pragma unroll
    for (int i=0;i<2;i++)
        #pragma unroll
        for (int u=0;u<8;u++) a0[i][u] = b1s[8*jg+u];
    #pragma unroll
    for (int k=0;k<8;k++){
        float e_a = embs[ea][k], e_b = embs[eb][k];
        #pragma unroll
        for (int u=0;u<8;u++){
            float wv = w1s[k*64 + 8*jg + u];
            a0[0][u] = fmaf(e_a, wv, a0[0][u]);
            a0[1][u] = fmaf(e_b, wv, a0[1][u]);
        }
    }
    #pragma unroll
    for (int i=0;i<2;i++){
        int e = ea + i;
        float4 p0 = make_float4(silu_f(a0[i][0]), silu_f(a0[i][1]), silu_f(a0[i][2]), silu_f(a0[i][3]));
        float4 p1 = make_float4(silu_f(a0[i][4]), silu_f(a0[i][5]), silu_f(a0[i][6]), silu_f(a0[i][7]));
        *(float4*)&hs[e][8*jg]     = p0;
        *(float4*)&hs[e][8*jg + 4] = p1;
    }
    __syncthreads();

    float a1[2][8];
    #pragma unroll
    for (int i=0;i<2;i++)
        #pragma unroll
        for (int u=0;u<8;u++) a1[i][u] = b2s[8*jg+u];
    #pragma unroll
    for (int k=0;k<64;k++){
        float h_a = hs[ea][k], h_b = hs[eb][k];
        float4 wA = *(const float4*)&w2s[k*64 + 8*jg];
        float4 wB = *(const float4*)&w2s[k*64 + 8*jg + 4];
        a1[0][0]=fmaf(h_a,wA.x,a1[0][0]); a1[0][1]=fmaf(h_a,wA.y,a1[0][1]);
        a1[0][2]=fmaf(h_a,wA.z,a1[0][2]); a1[0][3]=fmaf(h_a,wA.w,a1[0][3]);
        a1[0][4]=fmaf(h_a,wB.x,a1[0][4]); a1[0][5]=fmaf(h_a,wB.y,a1[0][5]);
        a1[0][6]=fmaf(h_a,wB.z,a1[0][6]); a1[0][7]=fmaf(h_a,wB.w,a1[0][7]);
        a1[1][0]=fmaf(h_b,wA.x,a1[1][0]); a1[1][1]=fmaf(h_b,wA.y,a1[1][1]);
        a1[1][2]=fmaf(h_b,wA.z,a1[1][2]); a1[1][3]=fmaf(h_b,wA.w,a1[1][3]);
        a1[1][4]=fmaf(h_b,wB.x,a1[1][4]); a1[1][5]=fmaf(h_b,wB.y,a1[1][5]);
        a1[1][6]=fmaf(h_b,wB.z,a1[1][6]); a1[1][7]=fmaf(h_b,wB.w,a1[1][7]);
    }
    __syncthreads();
    #pragma unroll
    for (int i=0;i<2;i++){
        int e = ea + i;
        float4 p0 = make_float4(silu_f(a1[i][0]), silu_f(a1[i][1]), silu_f(a1[i][2]), silu_f(a1[i][3]));
        float4 p1 = make_float4(silu_f(a1[i][4]), silu_f(a1[i][5]), silu_f(a1[i][6]), silu_f(a1[i][7]));
        *(float4*)&hs[e][8*jg]     = p0;
        *(float4*)&hs[e][8*jg + 4] = p1;
    }
    __syncthreads();

    float c2[2][18];
    #pragma unroll
    for (int i=0;i<2;i++)
        #pragma unroll
        for (int u=0;u<18;u++) c2[i][u] = b3s[18*jg+u];

    float* w3c = w2s;
    for (int ch=0; ch<4; ++ch){
        const float4* src = (const float4*)(W3 + 16*ch*144);
        float4* dst = (float4*)w3c;
        dst[t]       = src[t];
        dst[t+256]   = src[t+256];
        if (t < 64) dst[t+512] = src[t+512];
        __syncthreads();
        #pragma unroll
        for (int kk=0;kk<16;kk++){
            int k = 16*ch + kk;
            float h_a = hs[ea][k], h_b = hs[eb][k];
            #pragma unroll
            for (int u2=0;u2<9;u2++){
                float2 wv = *(const float2*)&w3c[kk*144 + 18*jg + 2*u2];
                c2[0][2*u2]   = fmaf(h_a, wv.x, c2[0][2*u2]);
                c2[0][2*u2+1] = fmaf(h_a, wv.y, c2[0][2*u2+1]);
                c2[1][2*u2]   = fmaf(h_b, wv.x, c2[1][2*u2]);
                c2[1][2*u2+1] = fmaf(h_b, wv.y, c2[1][2*u2+1]);
            }
        }
        __syncthreads();
    }
    #pragma unroll
    for (int i=0;i<2;i++){
        float* wo = wbuf + (size_t)slots[ea+i]*WROW + 18*jg;
        #pragma unroll
        for (int u2=0;u2<9;u2++)
            *(float2*)(wo + 2*u2) = make_float2(c2[i][2*u2], c2[i][2*u2+1]);
    }
    // append Y1/Y2 (geom floats 8..15) to the CSR row
    if (t < 128){
        int e = t >> 1, half = t & 1;
        *(float4*)(wbuf + (size_t)slots[e]*WROW + 144 + half*4) =
            *((const float4*)geom + (size_t)(e0+e)*4 + 2 + half);
    }
}

// ---------------- K6: per-dst gather + fused node update
// 256 threads = 4 waves; edge stream is fully CSR-ordered (wbuf row holds w+Y, srcp holds src)
__launch_bounds__(256, 8)
__global__ void k_gather(const int* __restrict__ rowp, const int* __restrict__ srcp,
                         const float* __restrict__ wbuf,
                         const float* __restrict__ s_in, const float* __restrict__ v_in,
                         const float* __restrict__ q_in,
                         float* __restrict__ s_out, float* __restrict__ v_out,
                         float* __restrict__ q_out,
                         const float* __restrict__ Wm0, const float* __restrict__ Wm1,
                         const float* __restrict__ Wm2,
                         const float* __restrict__ Ws0, const float* __restrict__ Ws1,
                         const float* __restrict__ Ws2,
                         const float* __restrict__ Wg, const float* __restrict__ bg,
                         int layer){
    __shared__ float pacc[4][400];
    __shared__ float lacc[400];
    __shared__ float lns[32];
    __shared__ float lgate[24];
    const int n = blockIdx.x;
    const int t = threadIdx.x;
    const int w = t >> 6;        // 0..3
    const int lane = t & 63;

    int s0_w, s0_o, s0_ob;
    if (lane < 32){ s0_w = lane;            s0_o = lane;          s0_ob = lane; }
    else if (lane < 48){ s0_w = 112+(lane-32); s0_o = 3*(lane-32); s0_ob = lane; }
    else if (lane < 56){ s0_w = 136+(lane-48); s0_o = 5*(lane-48); s0_ob = lane; }
    else { int R = lane-56; s0_w = 32+R; s0_o = R; s0_ob = 56+3*R; }
    int s1_w, s1_o, s1_ob;
    if (lane < 24){ int R = lane+8; s1_w = 32+R; s1_o = R;     s1_ob = 56+3*R; }
    else if (lane < 40){ int j = lane-24; s1_w = 96+j; s1_o = 3*j; s1_ob = 152+3*j; }
    else { int R = lane-40; s1_w = 64+R; s1_o = R; s1_ob = 200+5*R; }
    int s2_w, s2_o, s2_ob;
    if (lane < 8){ int R = lane+24; s2_w = 64+R; s2_o = R;   s2_ob = 200+5*R; }
    else { int j = lane-8; s2_w = 128+j; s2_o = 5*j; s2_ob = 360+5*j; }

    float a0[3] = {0.f,0.f,0.f};
    float a1[5] = {0.f,0.f,0.f,0.f,0.f};
    float a2[5] = {0.f,0.f,0.f,0.f,0.f};

    auto body = [&](int idx){
        const float* wp = wbuf + (size_t)idx*WROW;   // induction-only address: prefetchable
        int src = srcp[idx];
        float4 y14 = *(const float4*)(wp + 144);
        float4 y58 = *(const float4*)(wp + 148);
        const float* sp = s_in + (size_t)src*32;
        const float* vp = v_in + (size_t)src*48;
        const float* qp = q_in + (size_t)src*40;
        {
            float wv = wp[s0_w];
            if (lane < 32){
                a0[0] = fmaf(wv, sp[s0_o], a0[0]);
            } else if (lane < 48){
                float dv = vp[s0_o]*y14.x + vp[s0_o+1]*y14.y + vp[s0_o+2]*y14.z;
                a0[0] = fmaf(wv*ISQ3, dv, a0[0]);
            } else if (lane < 56){
                float dq = qp[s0_o]*y14.w + qp[s0_o+1]*y58.x + qp[s0_o+2]*y58.y
                         + qp[s0_o+3]*y58.z + qp[s0_o+4]*y58.w;
                a0[0] = fmaf(wv*ISQ5, dq, a0[0]);
            } else {
                float tmp = wv * sp[s0_o];
                a0[0] = fmaf(tmp, y14.x, a0[0]);
                a0[1] = fmaf(tmp, y14.y, a0[1]);
                a0[2] = fmaf(tmp, y14.z, a0[2]);
            }
        }
        {
            float wv = wp[s1_w];
            if (lane < 24){
                float tmp = wv * sp[s1_o];
                a1[0] = fmaf(tmp, y14.x, a1[0]);
                a1[1] = fmaf(tmp, y14.y, a1[1]);
                a1[2] = fmaf(tmp, y14.z, a1[2]);
            } else if (lane < 40){
                a1[0] = fmaf(wv, vp[s1_o],   a1[0]);
                a1[1] = fmaf(wv, vp[s1_o+1], a1[1]);
                a1[2] = fmaf(wv, vp[s1_o+2], a1[2]);
            } else {
                float tmp = wv * sp[s1_o];
                a1[0] = fmaf(tmp, y14.w, a1[0]);
                a1[1] = fmaf(tmp, y58.x, a1[1]);
                a1[2] = fmaf(tmp, y58.y, a1[2]);
                a1[3] = fmaf(tmp, y58.z, a1[3]);
                a1[4] = fmaf(tmp, y58.w, a1[4]);
            }
        }
        if (lane < 16){
            float wv = wp[s2_w];
            if (lane < 8){
                float tmp = wv * sp[s2_o];
                a2[0] = fmaf(tmp, y14.w, a2[0]);
                a2[1] = fmaf(tmp, y58.x, a2[1]);
                a2[2] = fmaf(tmp, y58.y, a2[2]);
                a2[3] = fmaf(tmp, y58.z, a2[3]);
                a2[4] = fmaf(tmp, y58.w, a2[4]);
            } else {
                a2[0] = fmaf(wv, qp[s2_o],   a2[0]);
                a2[1] = fmaf(wv, qp[s2_o+1], a2[1]);
                a2[2] = fmaf(wv, qp[s2_o+2], a2[2]);
                a2[3] = fmaf(wv, qp[s2_o+3], a2[3]);
                a2[4] = fmaf(wv, qp[s2_o+4], a2[4]);
            }
        }
    };

    const int beg = rowp[n], end = rowp[n+1];
    int idx = beg + w;
    for (; idx + 4 < end; idx += 8){   // both bodies in one BB -> interleaved loads (2-edge MLP)
        body(idx);
        body(idx + 4);
    }
    if (idx < end) body(idx);

    pacc[w][s0_ob] = a0[0];
    if (lane >= 56){ pacc[w][s0_ob+1] = a0[1]; pacc[w][s0_ob+2] = a0[2]; }
    pacc[w][s1_ob] = a1[0]; pacc[w][s1_ob+1] = a1[1]; pacc[w][s1_ob+2] = a1[2];
    if (lane >= 40){ pacc[w][s1_ob+3] = a1[3]; pacc[w][s1_ob+4] = a1[4]; }
    if (lane < 16){
        #pragma unroll
        for (int u=0;u<5;u++) pacc[w][s2_ob+u] = a2[u];
    }
    __syncthreads();
    for (int c=t; c<400; c+=256)
        lacc[c] = (pacc[0][c]+pacc[1][c]+pacc[2][c]+pacc[3][c]) * INV_AVG;
    __syncthreads();

    const float* Wm0p = Wm0 + layer*(56*32);
    const float* Ws0p = Ws0 + layer*(32*32);
    const float* Wm1p = Wm1 + layer*(48*16);
    const float* Ws1p = Ws1 + layer*(16*16);
    const float* Wm2p = Wm2 + layer*(40*8);
    const float* Ws2p = Ws2 + layer*(8*8);
    const float* Wgp  = Wg  + layer*(32*24);
    const float* bgp  = bg  + layer*24;

    float nvv = 0.f, nqv = 0.f;
    if (t < 32){
        float a = 0.f;
        #pragma unroll
        for (int c=0;c<56;c++) a = fmaf(lacc[c], Wm0p[c*32+t], a);
        #pragma unroll
        for (int c=0;c<32;c++) a = fmaf(s_in[n*32+c], Ws0p[c*32+t], a);
        lns[t] = a;
    } else if (t >= 64 && t < 112){
        int o = t-64, o3 = o/3, m3 = o-3*o3;
        #pragma unroll
        for (int c=0;c<48;c++) nvv = fmaf(lacc[56+c*3+m3], Wm1p[c*16+o3], nvv);
        #pragma unroll
        for (int c=0;c<16;c++) nvv = fmaf(v_in[n*48+c*3+m3], Ws1p[c*16+o3], nvv);
    } else if (t >= 128 && t < 168){
        int o = t-128, o5 = o/5, m5 = o-5*o5;
        #pragma unroll
        for (int c=0;c<40;c++) nqv = fmaf(lacc[200+c*5+m5], Wm2p[c*8+o5], nqv);
        #pragma unroll
        for (int c=0;c<8;c++)  nqv = fmaf(q_in[n*40+c*5+m5], Ws2p[c*8+o5], nqv);
    }
    __syncthreads();
    if (t < 24){
        float a = bgp[t];
        #pragma unroll
        for (int c=0;c<32;c++) a = fmaf(lns[c], Wgp[c*24+t], a);
        lgate[t] = sigmoid_f(a);
    }
    __syncthreads();
    if (t < 32){
        s_out[n*32+t] = s_in[n*32+t] + silu_f(lns[t]);
    } else if (t >= 64 && t < 112){
        int o = t-64;
        v_out[n*48+o] = v_in[n*48+o] + nvv * lgate[o/3];
    } else if (t >= 128 && t < 168){
        int o = t-128;
        q_out[n*40+o] = q_in[n*40+o] + nqv * lgate[16+o/5];
    }
}

// ---------------- K7: pooling MLP -> per-node logit
__launch_bounds__(128)
__global__ void k_pool(const float* __restrict__ s_in,
                       const float* __restrict__ Wp1, const float* __restrict__ bp1,
                       const float* __restrict__ Wp2, const float* __restrict__ bp2,
                       const float* __restrict__ Wp3, const float* __restrict__ bp3,
                       float* __restrict__ logits){
    __shared__ float ls[32];
    __shared__ float lh[128];
    __shared__ float wred[2];
    int n = blockIdx.x, t = threadIdx.x;
    if (t < 32) ls[t] = s_in[n*32+t];
    __syncthreads();
    float a = bp1[t];
    #pragma unroll
    for (int c=0;c<32;c++) a = fmaf(ls[c], Wp1[c*128+t], a);
    lh[t] = silu_f(a);
    __syncthreads();
    float b = bp2[t];
    #pragma unroll
    for (int k=0;k<128;k++) b = fmaf(lh[k], Wp2[k*128+t], b);
    float p = silu_f(b) * Wp3[t];
    #pragma unroll
    for (int off=32; off>0; off>>=1) p += __shfl_down(p, off, 64);
    if ((t & 63) == 0) wred[t>>6] = p;
    __syncthreads();
    if (t == 0) logits[n] = wred[0] + wred[1] + bp3[0];
}

// ---------------- K8r: batch ranges (batch is sorted)
__global__ void k_ranges(const int* __restrict__ batch, int* __restrict__ rs, int* __restrict__ re){
    int n = blockIdx.x*256 + threadIdx.x;
    if (n >= NN) return;
    int b = batch[n];
    if (n == 0 || batch[n-1] != b) rs[b] = n;
    if (n == NN-1 || batch[n+1] != b) re[b] = n+1;
}

// ---------------- K8: fused softmax-attention pool
__launch_bounds__(1024)
__global__ void k_spool(const float* __restrict__ logits, const float* __restrict__ s_in,
                        const int* __restrict__ rs, const int* __restrict__ re,
                        float* __restrict__ gpool){
    __shared__ float red[1024];
    __shared__ float racc[32*33];
    __shared__ float dred[32];
    __shared__ float smx;
    int b = blockIdx.x, t = threadIdx.x;
    int lo = rs[b], hi = re[b];
    float m = -3.0e38f;
    for (int n = lo + t; n < hi; n += 1024) m = fmaxf(m, logits[n]);
    red[t] = m; __syncthreads();
    for (int s2=512; s2>0; s2>>=1){ if (t<s2) red[t] = fmaxf(red[t], red[t+s2]); __syncthreads(); }
    if (t==0) smx = red[0];
    __syncthreads();
    float mx = smx;
    int g = t >> 5, c = t & 31;
    float acc = 0.f, zs = 0.f;
    for (int n = lo + g; n < hi; n += 32){
        float z = __expf(logits[n] - mx);
        acc = fmaf(z, s_in[n*32+c], acc);
        zs += z;
    }
    racc[g*33+c] = acc;
    if (c == 0) dred[g] = zs;
    __syncthreads();
    if (t < 32){
        float a = 0.f, d = 0.f;
        #pragma unroll
        for (int g2=0; g2<32; g2++){ a += racc[g2*33+t]; d += dred[g2]; }
        gpool[b*32+t] = a / d;
    }
}

// ---------------- K9a: h = silu(LN(gpool@Wo1+bo1))
__launch_bounds__(1024)
__global__ void k_out1(const float* __restrict__ gpool, const float* __restrict__ Wo1,
                       const float* __restrict__ bo1, const float* __restrict__ g1,
                       const float* __restrict__ be1, float* __restrict__ hbuf){
    __shared__ float lg[32];
    __shared__ float red[1024];
    __shared__ float stats[2];
    int b = blockIdx.x, t = threadIdx.x;
    if (t < 32) lg[t] = gpool[b*32+t];
    __syncthreads();
    float a = bo1[t];
    #pragma unroll
    for (int c=0;c<32;c++) a = fmaf(lg[c], Wo1[c*1024+t], a);
    red[t] = a; __syncthreads();
    for (int s2=512; s2>0; s2>>=1){ if (t<s2) red[t]+=red[t+s2]; __syncthreads(); }
    if (t==0) stats[0] = red[0]*(1.0f/1024.0f);
    __syncthreads();
    float mean = stats[0];
    float d = a - mean;
    red[t] = d*d; __syncthreads();
    for (int s2=512; s2>0; s2>>=1){ if (t<s2) red[t]+=red[t+s2]; __syncthreads(); }
    if (t==0) stats[1] = red[0]*(1.0f/1024.0f);
    __syncthreads();
    float rstd = rsqrtf(stats[1] + 1e-5f);
    hbuf[b*1024+t] = silu_f(d*rstd*g1[t] + be1[t]);
}

// ---------------- K9b: out = LN(h@Wo2+bo2), split-k=2
__launch_bounds__(1024)
__global__ void k_out2(const float* __restrict__ hbuf, const float* __restrict__ Wo2,
                       const float* __restrict__ bo2, const float* __restrict__ g2,
                       const float* __restrict__ be2, float* __restrict__ out){
    __shared__ float lh[1024];
    __shared__ float part[1024];
    __shared__ float red[1024];
    __shared__ float stats[2];
    int b = blockIdx.x, t = threadIdx.x;
    lh[t] = hbuf[b*1024 + t];
    __syncthreads();
    int j = t & 511, half = t >> 9;
    float a = (half == 0) ? bo2[j] : 0.0f;
    int k0 = half*512;
    #pragma unroll 8
    for (int k=0;k<512;k++) a = fmaf(lh[k0+k], Wo2[(size_t)(k0+k)*512 + j], a);
    part[t] = a; __syncthreads();
    float y = 0.f;
    if (t < 512) y = part[t] + part[t+512];
    red[t] = (t < 512) ? y : 0.f; __syncthreads();
    for (int s2=512; s2>0; s2>>=1){ if (t<s2) red[t]+=red[t+s2]; __syncthreads(); }
    if (t==0) stats[0] = red[0]*(1.0f/512.0f);
    __syncthreads();
    float mean = stats[0];
    float d = y - mean;
    red[t] = (t < 512) ? d*d : 0.f; __syncthreads();
    for (int s2=512; s2>0; s2>>=1){ if (t<s2) red[t]+=red[t+s2]; __syncthreads(); }
    if (t==0) stats[1] = red[0]*(1.0f/512.0f);
    __syncthreads();
    float rstd = rsqrtf(stats[1] + 1e-5f);
    if (t < 512) out[b*512+t] = d*rstd*g2[t] + be2[t];
}

extern "C" void kernel_launch(void* const* d_in, const int* in_sizes, int n_in,
                              void* d_out, int out_size, void* d_ws, size_t ws_size,
                              hipStream_t stream){
    const float* x   = (const float*)d_in[0];
    const float* pos = (const float*)d_in[1];
    const float* Win = (const float*)d_in[2];
    const float* Wr1 = (const float*)d_in[3];
    const float* br1 = (const float*)d_in[4];
    const float* Wr2 = (const float*)d_in[5];
    const float* br2 = (const float*)d_in[6];
    const float* Wr3 = (const float*)d_in[7];
    const float* br3 = (const float*)d_in[8];
    const float* Wm0 = (const float*)d_in[9];
    const float* Wm1 = (const float*)d_in[10];
    const float* Wm2 = (const float*)d_in[11];
    const float* Ws0 = (const float*)d_in[12];
    const float* Ws1 = (const float*)d_in[13];
    const float* Ws2 = (const float*)d_in[14];
    const float* Wg  = (const float*)d_in[15];
    const float* bg  = (const float*)d_in[16];
    const float* Wp1 = (const float*)d_in[17];
    const float* bp1 = (const float*)d_in[18];
    const float* Wp2 = (const float*)d_in[19];
    const float* bp2 = (const float*)d_in[20];
    const float* Wp3 = (const float*)d_in[21];
    const float* bp3 = (const float*)d_in[22];
    const float* Wo1 = (const float*)d_in[23];
    const float* bo1 = (const float*)d_in[24];
    const float* g1  = (const float*)d_in[25];
    const float* be1 = (const float*)d_in[26];
    const float* Wo2 = (const float*)d_in[27];
    const float* bo2 = (const float*)d_in[28];
    const float* g2  = (const float*)d_in[29];
    const float* be2 = (const float*)d_in[30];
    const int* ei    = (const int*)d_in[31];
    const int* batch = (const int*)d_in[32];
    float* out = (float*)d_out;

    char* wsb = (char*)d_ws;
    size_t off = 0;
    auto take = [&](size_t bytes)->char*{
        char* p = wsb + off;
        off = (off + bytes + 255) & ~(size_t)255;
        return p;
    };
    float* geom  = (float*)take((size_t)NE*16*4);
    float* wbuf  = (float*)take((size_t)NE*WROW*4);
    int*   rowp  = (int*)take((size_t)(NN+1)*4);
    int*   fpos  = (int*)take((size_t)NN*4);
    int*   slot  = (int*)take((size_t)NE*4);
    int*   srcp  = (int*)take((size_t)NE*4);
    // vA then qA contiguous -> one memset covers both
    float* vA = (float*)take((size_t)NN*48*4);
    float* qA = (float*)take((size_t)NN*40*4);
    float* sA = (float*)take((size_t)NN*32*4);
    float* sB = (float*)take((size_t)NN*32*4);
    float* vB = (float*)take((size_t)NN*48*4);
    float* qB = (float*)take((size_t)NN*40*4);
    float* logits = (float*)take((size_t)NN*4);
    int*   rs     = (int*)take(64);
    int*   re     = rs + 8;
    float* gpool  = (float*)take((size_t)NB_*32*4);
    float* hbuf   = (float*)take((size_t)NB_*1024*4);
    (void)ws_size; (void)in_sizes; (void)n_in; (void)out_size;

    hipMemsetAsync(rowp, 0, (size_t)(NN+1)*4, stream);
    hipMemsetAsync(vA,   0, (size_t)NN*48*4 + (size_t)NN*40*4, stream);
    hipMemsetAsync(rs,   0, 64, stream);

    k_geom<<<(NE+255)/256, 256, 0, stream>>>(pos, ei, geom, rowp);
    k_scan<<<1, 256, 0, stream>>>(rowp, fpos);
    k_fill<<<(NE+255)/256, 256, 0, stream>>>(ei, fpos, slot, srcp);
    k_sinit<<<(NN*32+255)/256, 256, 0, stream>>>(x, Win, sA);
    k_ranges<<<(NN+255)/256, 256, 0, stream>>>(batch, rs, re);

    float* si=sA; float* so=sB; float* vi=vA; float* vo=vB; float* qi=qA; float* qo=qB;
    for (int layer=0; layer<4; ++layer){
        k_mlp<<<NE/64, 256, 0, stream>>>(geom, slot, Wr1, br1, Wr2, br2, Wr3, br3, wbuf, layer);
        k_gather<<<NN, 256, 0, stream>>>(rowp, srcp, wbuf, si, vi, qi, so, vo, qo,
                                         Wm0, Wm1, Wm2, Ws0, Ws1, Ws2, Wg, bg, layer);
        float* ts=si; si=so; so=ts;
        float* tv=vi; vi=vo; vo=tv;
        float* tq=qi; qi=qo; qo=tq;
    }
    k_pool<<<NN, 128, 0, stream>>>(si, Wp1, bp1, Wp2, bp2, Wp3, bp3, logits);
    k_spool<<<NB_, 1024, 0, stream>>>(logits, si, rs, re, gpool);
    k_out1<<<NB_, 1024, 0, stream>>>(gpool, Wo1, bo1, g1, be1, hbuf);
    k_out2<<<NB_, 1024, 0, stream>>>(hbuf, Wo2, bo2, g2, be2, out);
}